// Round 4
// baseline (388.817 us; speedup 1.0000x reference)
//
#include <hip/hip_runtime.h>
#include <stdint.h>

#define M_DIM 16384
#define N_DIM 4096
#define K_DIM 4096

#define BM 256
#define BN 256
#define BK 128
#define NT (K_DIM / BK)  // 32 K-tiles

typedef int i32x4 __attribute__((ext_vector_type(4)));
typedef int i32x16 __attribute__((ext_vector_type(16)));

// ---- async global->LDS 16B (dest = wave-uniform base, HW adds lane*16) ----
__device__ __forceinline__ void async16(const uint8_t* g, uint8_t* l) {
    __builtin_amdgcn_global_load_lds(
        (const __attribute__((address_space(1))) void*)g,
        (__attribute__((address_space(3))) void*)l,
        16, 0, 0);
}

// ---------------- weight pack: int32 -> int8 ----------------
__global__ __launch_bounds__(256) void pack_w_kernel(const int* __restrict__ w32,
                                                     uint32_t* __restrict__ w8,
                                                     int n4) {
    int i = blockIdx.x * 256 + threadIdx.x;
    if (i < n4) {
        const int4 v = reinterpret_cast<const int4*>(w32)[i];
        uint32_t p = (uint32_t)(v.x & 255) | ((uint32_t)(v.y & 255) << 8) |
                     ((uint32_t)(v.z & 255) << 16) | ((uint32_t)(v.w & 255) << 24);
        w8[i] = p;
    }
}

// ---------------- per-row dynamic activation quant ----------------
__global__ __launch_bounds__(256) void quant_kernel(const float* __restrict__ x,
                                                    uint32_t* __restrict__ xq,
                                                    float* __restrict__ xscale) {
    const int m = blockIdx.x;
    const int t = threadIdx.x;
    const float4* row = reinterpret_cast<const float4*>(x + (size_t)m * K_DIM);
    float4 v[4];
    float amax = 0.0f;
#pragma unroll
    for (int i = 0; i < 4; ++i) {
        v[i] = row[t + i * 256];
        amax = fmaxf(amax, fmaxf(fmaxf(fabsf(v[i].x), fabsf(v[i].y)),
                                 fmaxf(fabsf(v[i].z), fabsf(v[i].w))));
    }
#pragma unroll
    for (int off = 32; off > 0; off >>= 1) amax = fmaxf(amax, __shfl_xor(amax, off));
    __shared__ float smax[4];
    if ((t & 63) == 0) smax[t >> 6] = amax;
    __syncthreads();
    amax = fmaxf(fmaxf(smax[0], smax[1]), fmaxf(smax[2], smax[3]));
    const float scale = amax / 127.0f;
    const float s = fmaxf(scale, 1e-8f);
    if (t == 0) xscale[m] = scale;
    uint32_t* orow = xq + (size_t)m * (K_DIM / 4);
#pragma unroll
    for (int i = 0; i < 4; ++i) {
        int q0 = __float2int_rn(v[i].x / s);
        int q1 = __float2int_rn(v[i].y / s);
        int q2 = __float2int_rn(v[i].z / s);
        int q3 = __float2int_rn(v[i].w / s);
        q0 = max(-127, min(127, q0));
        q1 = max(-127, min(127, q1));
        q2 = max(-127, min(127, q2));
        q3 = max(-127, min(127, q3));
        uint32_t p = (uint32_t)(q0 & 255) | ((uint32_t)(q1 & 255) << 8) |
                     ((uint32_t)(q2 & 255) << 16) | ((uint32_t)(q3 & 255) << 24);
        orow[t + i * 256] = p;
    }
}

// ---------------- int8 GEMM, 256x256, 32x32x32 MFMA, 2 fat phases/tile ----
// 512 threads = 8 waves (2M x 4N), per-wave output 128x64 -> acc[4][2] i32x16.
// K-tile BK=128 = 4 k-steps of 32. LDS: 2 x (A 32KB + B 32KB) = 128KB.
// Tile t uses buf(t&1). Phase layout (uniform vmcnt(8) guard at phase end):
//  PH0: read A0(8),B0(4) | pin | B1(4); stage A1(t+1)->other [2 loads]; BAR;
//       lgkm(4); 8 MFMA A0xB0; lgkm(0); 8 MFMA A0xB1; vmcnt(8); BAR
//  PH1: read A1(8); stage A0,B0,B1(t+2)->same [6 loads]; BAR;
//       lgkm(0); 16 MFMA A1x{B1,B0}; vmcnt(8); BAR
// Guard math: any region's data is staged with exactly 8 loads issued after
// it by the time its reads issue -> vmcnt(8) waits precisely for it.
// Swizzle: LDS(row r, unit p) holds global unit p^(r&7) (pre-swizzled source,
// linear LDS dest, XOR on ds_read). Verified 0 bank conflicts in r1-r3.
__global__ __launch_bounds__(512, 2) void gemm_kernel(
    const uint8_t* __restrict__ Aq, const float* __restrict__ ascale,
    const uint8_t* __restrict__ Bq, const float* __restrict__ wscale,
    float* __restrict__ out) {
    __shared__ uint8_t lds[2 * BM * BK + 2 * BN * BK];
    uint8_t* ldsA0 = lds;
    uint8_t* ldsA1 = lds + BM * BK;
    uint8_t* ldsB0 = lds + 2 * BM * BK;
    uint8_t* ldsB1 = lds + 2 * BM * BK + BN * BK;

    const int tid = threadIdx.x;
    const int lane = tid & 63;
    const int w = tid >> 6;
    const int wr = w >> 2;     // 0..1 -> M offset wr*128
    const int wc = w & 3;      // 0..3 -> N offset wc*64
    const int l31 = lane & 31; // row/col within 32x32 fragment
    const int hi = lane >> 5;  // k-half selector
    const int aa = lane >> 3;  // staging: row-within-8
    const int pp = lane & 7;   // staging: unit-within-row

    // XCD-aware bijective swizzle (1024 blocks, 1024%8==0)
    const int bid = blockIdx.x;
    const int swz = (bid & 7) * (1024 / 8) + (bid >> 3);
    const size_t row0 = (size_t)(swz >> 4) * BM;  // 64 M-tiles
    const size_t col0 = (size_t)(swz & 15) * BN;  // 16 N-tiles
    const uint8_t* Ab = Aq + row0 * K_DIM;
    const uint8_t* Bb = Bq + col0 * K_DIM;

    i32x16 acc[4][2];
#pragma unroll
    for (int i = 0; i < 4; ++i)
#pragma unroll
        for (int j = 0; j < 2; ++j) acc[i][j] = (i32x16)(0);

#define STAGE_A(DST, KT, MH)                                                     \
    do {                                                                         \
        _Pragma("unroll") for (int it_ = 0; it_ < 2; ++it_) {                    \
            const int m_ = (MH) * 64 + w * 8 + aa + it_ * 128;                   \
            async16(Ab + (size_t)m_ * K_DIM + (KT) * BK + ((pp ^ aa) << 4),      \
                    (DST) + ((MH) * 64 + w * 8 + it_ * 128) * BK);               \
        }                                                                        \
    } while (0)

#define STAGE_B(DST, KT, NH)                                                     \
    do {                                                                         \
        _Pragma("unroll") for (int it_ = 0; it_ < 2; ++it_) {                    \
            const int rwh_ = it_ * 64 + w * 8 + aa;                              \
            const int n_ = (NH) * 32 + (rwh_ & 31) + ((rwh_ >> 5) << 6);         \
            const int rw0_ = it_ * 64 + w * 8;                                   \
            const int nb_ = (NH) * 32 + (rw0_ & 31) + ((rw0_ >> 5) << 6);        \
            async16(Bb + (size_t)n_ * K_DIM + (KT) * BK + ((pp ^ aa) << 4),      \
                    (DST) + nb_ * BK);                                           \
        }                                                                        \
    } while (0)

    // A frag: lane holds row l31 of 32-row block, 16 k-bytes at hi*16 + ks*32
#define READ_A32(BUF, MH)                                                        \
    do {                                                                         \
        _Pragma("unroll") for (int mf_ = 0; mf_ < 2; ++mf_)                      \
        _Pragma("unroll") for (int ks_ = 0; ks_ < 4; ++ks_) {                    \
            const int r_ = wr * 128 + (MH) * 64 + mf_ * 32 + l31;                \
            const int u_ = ks_ * 2 + hi;                                         \
            af[mf_][ks_] = *reinterpret_cast<const i32x4*>(                      \
                (BUF) + r_ * BK + ((u_ ^ (r_ & 7)) << 4));                       \
        }                                                                        \
    } while (0)

#define READ_B32(BUF, NH, DSTF)                                                  \
    do {                                                                         \
        _Pragma("unroll") for (int ks_ = 0; ks_ < 4; ++ks_) {                    \
            const int r_ = wc * 64 + (NH) * 32 + l31;                            \
            const int u_ = ks_ * 2 + hi;                                         \
            DSTF[ks_] = *reinterpret_cast<const i32x4*>(                         \
                (BUF) + r_ * BK + ((u_ ^ (r_ & 7)) << 4));                       \
        }                                                                        \
    } while (0)

#define CLUSTER8(MH, NH, BF)                                                     \
    do {                                                                         \
        __builtin_amdgcn_s_setprio(1);                                           \
        _Pragma("unroll") for (int ks_ = 0; ks_ < 4; ++ks_)                      \
        _Pragma("unroll") for (int mf_ = 0; mf_ < 2; ++mf_)                      \
            acc[(MH) * 2 + mf_][NH] = __builtin_amdgcn_mfma_i32_32x32x32_i8(     \
                af[mf_][ks_], BF[ks_], acc[(MH) * 2 + mf_][NH], 0, 0, 0);        \
        __builtin_amdgcn_s_setprio(0);                                           \
    } while (0)

#define CLUSTER16(MH)                                                            \
    do {                                                                         \
        __builtin_amdgcn_s_setprio(1);                                           \
        _Pragma("unroll") for (int ks_ = 0; ks_ < 4; ++ks_)                      \
        _Pragma("unroll") for (int mf_ = 0; mf_ < 2; ++mf_) {                    \
            acc[(MH) * 2 + mf_][1] = __builtin_amdgcn_mfma_i32_32x32x32_i8(      \
                af[mf_][ks_], bf1[ks_], acc[(MH) * 2 + mf_][1], 0, 0, 0);        \
            acc[(MH) * 2 + mf_][0] = __builtin_amdgcn_mfma_i32_32x32x32_i8(      \
                af[mf_][ks_], bf0[ks_], acc[(MH) * 2 + mf_][0], 0, 0, 0);        \
        }                                                                        \
        __builtin_amdgcn_s_setprio(0);                                           \
    } while (0)

#define BAR __builtin_amdgcn_s_barrier()
#define SB0 __builtin_amdgcn_sched_barrier(0)
#define VMCNT8 asm volatile("s_waitcnt vmcnt(8)" ::: "memory")
#define LGKM(N) asm volatile("s_waitcnt lgkmcnt(" #N ")" ::: "memory")

    // ---- prologue (emulates steady-state in-flight structure) ----
    STAGE_A(ldsA0, 0, 0);  // tile0 A0,B0,B1 -> buf0   [6 loads]
    STAGE_B(ldsB0, 0, 0);
    STAGE_B(ldsB0, 0, 1);
    STAGE_A(ldsA0, 0, 1);  // tile0 A1 -> buf0         [2]
    STAGE_A(ldsA1, 1, 0);  // tile1 A0,B0,B1 -> buf1   [6]
    STAGE_B(ldsB1, 1, 0);
    STAGE_B(ldsB1, 1, 1);
    VMCNT8;  // tile0 A0,B0,B1 landed (8 issued after them)
    BAR;

    i32x4 af[2][4], bf0[4], bf1[4];

#pragma unroll 1
    for (int it2 = 0; it2 < NT / 2; ++it2) {
        const int t = 2 * it2;
        const int kt2 = (t + 2 < NT) ? t + 2 : NT - 1;  // clamped tail stages:
        const int kt3 = (t + 3 < NT) ? t + 3 : NT - 1;  // write dead regions only

        // ======== tile t (buf0) ========
        // PH0
        READ_A32(ldsA0, 0);
        READ_B32(ldsB0, 0, bf0);
        SB0;                        // pin: bf1 reads are the LAST 4 lgkm ops
        READ_B32(ldsB0, 1, bf1);
        STAGE_A(ldsA1, t + 1, 1);   // A1(t+1) -> buf1 [2]
        BAR;
        LGKM(4);  SB0;              // af+bf0 done (bf1's 4 outstanding)
        CLUSTER8(0, 0, bf0);
        LGKM(0);  SB0;              // bf1 done (landed under cluster)
        CLUSTER8(0, 1, bf1);
        VMCNT8;                     // A1(t) landed
        BAR;
        // PH1
        READ_A32(ldsA0, 1);
        STAGE_A(ldsA0, kt2, 0);     // A0,B0,B1(t+2) -> buf0 [6]
        STAGE_B(ldsB0, kt2, 0);
        STAGE_B(ldsB0, kt2, 1);
        BAR;
        LGKM(0);  SB0;
        CLUSTER16(1);
        VMCNT8;                     // A0,B0,B1(t+1) landed
        BAR;

        // ======== tile t+1 (buf1) ========
        // PH0
        READ_A32(ldsA1, 0);
        READ_B32(ldsB1, 0, bf0);
        SB0;
        READ_B32(ldsB1, 1, bf1);
        STAGE_A(ldsA0, kt2, 1);     // A1(t+2) -> buf0 [2]
        BAR;
        LGKM(4);  SB0;
        CLUSTER8(0, 0, bf0);
        LGKM(0);  SB0;
        CLUSTER8(0, 1, bf1);
        VMCNT8;                     // A1(t+1) landed
        BAR;
        // PH1
        READ_A32(ldsA1, 1);
        STAGE_A(ldsA1, kt3, 0);     // A0,B0,B1(t+3) -> buf1 [6]
        STAGE_B(ldsB1, kt3, 0);
        STAGE_B(ldsB1, kt3, 1);
        BAR;
        LGKM(0);  SB0;
        CLUSTER16(1);
        VMCNT8;                     // A0,B0,B1(t+2) landed
        BAR;
    }

    // ---- epilogue: 32x32 C/D layout: col=lane&31, row=(j&3)+8*(j>>2)+4*hi ----
    const float* asp = ascale + row0 + wr * 128;
    const float* wsp = wscale + col0 + wc * 64;
    float wsv[2];
#pragma unroll
    for (int nf = 0; nf < 2; ++nf) wsv[nf] = wsp[nf * 32 + l31];
    float* outBase = out + (row0 + wr * 128) * (size_t)N_DIM + col0 + wc * 64;
#pragma unroll
    for (int mf = 0; mf < 4; ++mf) {
#pragma unroll
        for (int j = 0; j < 16; ++j) {
            const int r = mf * 32 + (j & 3) + 8 * (j >> 2) + 4 * hi;
            const float av = asp[r];
            float* orow = outBase + (size_t)r * N_DIM;
#pragma unroll
            for (int nf = 0; nf < 2; ++nf) {
                orow[nf * 32 + l31] = (float)acc[mf][nf][j] * av * wsv[nf];
            }
        }
    }
#undef STAGE_A
#undef STAGE_B
#undef READ_A32
#undef READ_B32
#undef CLUSTER8
#undef CLUSTER16
#undef BAR
#undef SB0
#undef VMCNT8
#undef LGKM
}

extern "C" void kernel_launch(void* const* d_in, const int* in_sizes, int n_in,
                              void* d_out, int out_size, void* d_ws, size_t ws_size,
                              hipStream_t stream) {
    const float* x = (const float*)d_in[0];
    const int* w32 = (const int*)d_in[1];
    const float* wscale = (const float*)d_in[2];
    float* out = (float*)d_out;

    uint8_t* ws = (uint8_t*)d_ws;
    uint32_t* xq = (uint32_t*)ws;                                  // 64 MiB
    float* xscale = (float*)(ws + (size_t)M_DIM * K_DIM);          // 64 KiB
    uint8_t* wq = ws + (size_t)M_DIM * K_DIM + (size_t)M_DIM * 4;  // 16 MiB

    pack_w_kernel<<<dim3((N_DIM * K_DIM / 4 + 255) / 256), 256, 0, stream>>>(
        w32, (uint32_t*)wq, N_DIM * K_DIM / 4);
    quant_kernel<<<dim3(M_DIM), 256, 0, stream>>>(x, xq, xscale);
    gemm_kernel<<<dim3((M_DIM / BM) * (N_DIM / BN)), 512, 0, stream>>>(
        (const uint8_t*)xq, xscale, wq, wscale, out);
}